// Round 14
// baseline (258.590 us; speedup 1.0000x reference)
//
#include <hip/hip_runtime.h>

// ---------------------------------------------------------------------------
// DualGCN v16 = v14 revert (best known-good: 257.6us, absmax 3.5/4.18).
//   v15's fp8-only slabs overshot the accuracy gate (6.0 > 4.18) -> the
//   precision lever is exhausted at v14's operating point:
//   - fp8-e4m3 gather slabs (inputs to all 4 SpMMs), bf16 everywhere a GEMM
//     consumes an operand. 8 lanes/row x 16B uint4 gathers, packed-f32
//     accumulation (v_pk_fma_f32). Depth-2 col/val software pipeline.
//   - GEMM-side fusions: dual first-layer GEMM, chain (B->Q through LDS),
//     Wm+final fused (A3 never hits global).
// 6 launches. N=50000, E=800000, H=128, OUT=64.
// ---------------------------------------------------------------------------

typedef short short8 __attribute__((ext_vector_type(8)));
typedef float floatx4 __attribute__((ext_vector_type(4)));
typedef float floatx2 __attribute__((ext_vector_type(2)));

#define LDXP 136   // padded LDS row stride (bf16 units)

__device__ inline unsigned short f2bf(float f) {
  unsigned u = __builtin_bit_cast(unsigned, f);
  u += 0x7fffu + ((u >> 16) & 1u);      // round-to-nearest-even
  return (unsigned short)(u >> 16);
}
__device__ inline unsigned pack2(float a, float b) {
  return (unsigned)f2bf(a) | ((unsigned)f2bf(b) << 16);
}
__device__ inline float bf_lo(unsigned w) {
  return __builtin_bit_cast(float, w << 16);
}
__device__ inline float bf_hi(unsigned w) {
  return __builtin_bit_cast(float, w & 0xffff0000u);
}
// 4 floats -> 4 fp8 bytes (RNE, HW)
__device__ inline unsigned pack_fp8x4(float v0, float v1, float v2, float v3) {
  int p = 0;
  p = __builtin_amdgcn_cvt_pk_fp8_f32(v0, v1, p, false);   // bytes 0,1
  p = __builtin_amdgcn_cvt_pk_fp8_f32(v2, v3, p, true);    // bytes 2,3
  return (unsigned)p;
}

// y=0: rowptr for graph a; y=1: rowptr for graph b; y=2: convert weights.
// Wo de-interleaved into Wo0 = Wo[:, :128] and Wo1 = Wo[:, 128:].
__global__ __launch_bounds__(256) void setup_kernel(
    const int* __restrict__ rowA, const int* __restrict__ rowB,
    int E, int n, int* __restrict__ rpa, int* __restrict__ rpb,
    const float* __restrict__ Wa0, const float* __restrict__ Wa1,
    const float* __restrict__ Wb0, const float* __restrict__ Wb1,
    const float* __restrict__ Wm,  const float* __restrict__ Wo,
    unsigned short* __restrict__ Wout)
{
  if (blockIdx.y == 2) {
    for (int i = blockIdx.x * 256 + threadIdx.x; i < 131072; i += gridDim.x * 256) {
      float v;
      if      (i < 16384)  v = Wa0[i];
      else if (i < 32768)  v = Wa1[i - 16384];
      else if (i < 49152)  v = Wb0[i - 32768];
      else if (i < 65536)  v = Wb1[i - 49152];
      else if (i < 114688) v = Wm[i - 65536];
      else {
        int o = i - 114688;           // [0, 16384)
        int half = o >> 13;           // 0 -> Wo0, 1 -> Wo1
        int idx = o & 8191;
        int r = idx >> 7, c = idx & 127;
        v = Wo[r * 256 + half * 128 + c];
      }
      Wout[i] = f2bf(v);
    }
    return;
  }
  int i = blockIdx.x * blockDim.x + threadIdx.x;
  if (i > n) return;
  const int* row = blockIdx.y ? rowB : rowA;
  int* rp = blockIdx.y ? rpb : rpa;
  int lo = 0, hi = E;
  while (lo < hi) {
    int mid = (lo + hi) >> 1;
    if (row[mid] < i) lo = mid + 1; else hi = mid;
  }
  rp[i] = lo;
}

// ---------------------------------------------------------------------------
// SpMM row body, fp8 gathers, 16B/lane, packed-f32 accumulation.
// Y[g,:] = sum_e val[e] * X8[col[e],:]   (X8 fp8-e4m3, WIDTH features)
// WIDTH/16 lanes per row; each lane owns 16 features (8 floatx2 accums).
// Depth-2 pipeline: col/val prefetched 2 batches ahead.
// ---------------------------------------------------------------------------
template <int WIDTH, bool OUTF32>
__device__ __forceinline__ void spmm_rows_fp8(
    const int* __restrict__ rowptr, const int* __restrict__ col,
    const float* __restrict__ val, const unsigned char* __restrict__ X8,
    void* __restrict__ Yv, int n, int bx)
{
  constexpr int LPR = WIDTH / 16;       // lanes per row
  constexpr int GPB = 256 / LPR;        // row-groups per block
  int g = bx * GPB + ((int)threadIdx.x / LPR);
  int lane = threadIdx.x & (LPR - 1);
  if (g >= n) return;
  int e0 = rowptr[g], e1 = rowptr[g + 1];

  floatx2 ac[8];
#pragma unroll
  for (int k = 0; k < 8; ++k) ac[k] = (floatx2){0.f, 0.f};
  const size_t loff = (size_t)lane * 16;

  auto gat = [&](int c) -> uint4 {
    return *(const uint4*)(X8 + (size_t)c * WIDTH + loff);
  };
  auto fma1 = [&](float v, uint4 w) {
    const floatx2 vv = {v, v};
    floatx2 p;
    p = __builtin_amdgcn_cvt_pk_f32_fp8((int)w.x, false);
    ac[0] = __builtin_elementwise_fma(vv, p, ac[0]);
    p = __builtin_amdgcn_cvt_pk_f32_fp8((int)w.x, true);
    ac[1] = __builtin_elementwise_fma(vv, p, ac[1]);
    p = __builtin_amdgcn_cvt_pk_f32_fp8((int)w.y, false);
    ac[2] = __builtin_elementwise_fma(vv, p, ac[2]);
    p = __builtin_amdgcn_cvt_pk_f32_fp8((int)w.y, true);
    ac[3] = __builtin_elementwise_fma(vv, p, ac[3]);
    p = __builtin_amdgcn_cvt_pk_f32_fp8((int)w.z, false);
    ac[4] = __builtin_elementwise_fma(vv, p, ac[4]);
    p = __builtin_amdgcn_cvt_pk_f32_fp8((int)w.z, true);
    ac[5] = __builtin_elementwise_fma(vv, p, ac[5]);
    p = __builtin_amdgcn_cvt_pk_f32_fp8((int)w.w, false);
    ac[6] = __builtin_elementwise_fma(vv, p, ac[6]);
    p = __builtin_amdgcn_cvt_pk_f32_fp8((int)w.w, true);
    ac[7] = __builtin_elementwise_fma(vv, p, ac[7]);
  };
  auto accum = [&](int c, float v) { fma1(v, gat(c)); };

  int e = e0;
  int epro = (e0 + 3) & ~3;             // align to 4 for vector col/val loads
  if (epro > e1) epro = e1;
  for (; e < epro; ++e) accum(col[e], val[e]);

  int nb = (e1 - e) >> 2;               // full 4-edge batches
  if (nb > 0) {
    int4   cA = *(const int4*)(col + e);
    float4 vA = *(const float4*)(val + e);
    int4   cB = cA; float4 vB = vA;
    if (nb > 1) { cB = *(const int4*)(col + e + 4); vB = *(const float4*)(val + e + 4); }
    uint4 w0 = gat(cA.x), w1 = gat(cA.y), w2 = gat(cA.z), w3 = gat(cA.w);
    for (int t = 0; t < nb - 1; ++t) {
      int4 cC = cB; float4 vC = vB;
      if (t + 2 < nb) {
        cC = *(const int4*)(col + e + 4 * (t + 2));
        vC = *(const float4*)(val + e + 4 * (t + 2));
      }
      uint4 u0 = gat(cB.x), u1 = gat(cB.y), u2 = gat(cB.z), u3 = gat(cB.w);
      fma1(vA.x, w0); fma1(vA.y, w1); fma1(vA.z, w2); fma1(vA.w, w3);
      vA = vB; vB = vC; cB = cC;
      w0 = u0; w1 = u1; w2 = u2; w3 = u3;
    }
    fma1(vA.x, w0); fma1(vA.y, w1); fma1(vA.z, w2); fma1(vA.w, w3);
    e += nb * 4;
  }
  for (; e < e1; ++e) accum(col[e], val[e]);

  if (OUTF32) {
    float* Y = (float*)Yv;
#pragma unroll
    for (int q = 0; q < 4; ++q) {
      float4 o;
      o.x = ac[2 * q].x;     o.y = ac[2 * q].y;
      o.z = ac[2 * q + 1].x; o.w = ac[2 * q + 1].y;
      *(float4*)(Y + (size_t)g * WIDTH + lane * 16 + q * 4) = o;
    }
  } else {
    unsigned short* Y = (unsigned short*)Yv;
    uint4 o0, o1;
    o0.x = pack2(ac[0].x, ac[0].y); o0.y = pack2(ac[1].x, ac[1].y);
    o0.z = pack2(ac[2].x, ac[2].y); o0.w = pack2(ac[3].x, ac[3].y);
    o1.x = pack2(ac[4].x, ac[4].y); o1.y = pack2(ac[5].x, ac[5].y);
    o1.z = pack2(ac[6].x, ac[6].y); o1.w = pack2(ac[7].x, ac[7].y);
    *(uint4*)(Y + (size_t)g * WIDTH + lane * 16) = o0;
    *(uint4*)(Y + (size_t)g * WIDTH + lane * 16 + 8) = o1;
  }
}

// y=0: graph a, A8->B; y=1: graph b, C8->B2 (both 128-wide fp8 in, bf16 out)
__global__ __launch_bounds__(256) void spmm_dual128_kernel(
    const int* __restrict__ rpa, const int* __restrict__ cola,
    const float* __restrict__ vala, const unsigned char* __restrict__ A8,
    unsigned short* __restrict__ B,
    const int* __restrict__ rpb, const int* __restrict__ colb,
    const float* __restrict__ valb, const unsigned char* __restrict__ C8,
    unsigned short* __restrict__ B2, int n)
{
  if (blockIdx.y == 0)
    spmm_rows_fp8<128, false>(rpa, cola, vala, A8, B, n, blockIdx.x);
  else
    spmm_rows_fp8<128, false>(rpb, colb, valb, C8, B2, n, blockIdx.x);
}

// y=0: graph b 128-wide D8->Yb (bf16); y=1: graph a 64-wide Q8->Pout (f32)
__global__ __launch_bounds__(256) void spmm_mixed_kernel(
    const int* __restrict__ rpb, const int* __restrict__ colb,
    const float* __restrict__ valb, const unsigned char* __restrict__ D8,
    unsigned short* __restrict__ Yb,
    const int* __restrict__ rpa, const int* __restrict__ cola,
    const float* __restrict__ vala, const unsigned char* __restrict__ Q8,
    float* __restrict__ Pout, int n)
{
  if (blockIdx.y == 0)
    spmm_rows_fp8<128, false>(rpb, colb, valb, D8, Yb, n, blockIdx.x);
  else
    spmm_rows_fp8<64, true>(rpa, cola, vala, Q8, Pout, n, blockIdx.x);
}

// ---------------------------------------------------------------------------
// GEMM building blocks (v9 verbatim). Block: 256 thr = 4 waves 2x2;
// tile 128 rows x HOUT. X operand in LDS; W fragments from global.
// ---------------------------------------------------------------------------
__device__ inline void stage_bf16(const unsigned short* __restrict__ Xp,
                                  unsigned short* Xs, int row0, int n,
                                  int rloc, int c8)
{
#pragma unroll
  for (int p = 0; p < 8; ++p) {
    int r = p * 16 + rloc;
    int gr = row0 + r;
    uint4 v = make_uint4(0u, 0u, 0u, 0u);
    if (gr < n) v = *(const uint4*)(Xp + (size_t)gr * 128 + c8);
    *(uint4*)(Xs + r * LDXP + c8) = v;
  }
}

template <int NT>
__device__ inline void mfma_phase(const unsigned short* __restrict__ W, int wld,
                                  const unsigned short* Xs,
                                  int wm, int wn, int l15, int quad,
                                  floatx4 (&acc)[4][NT])
{
#pragma unroll
  for (int k0 = 0; k0 < 128; k0 += 32) {
    const int ko = k0 + quad * 8;
    short8 aW[NT], bX[4];
#pragma unroll
    for (int j = 0; j < NT; ++j)
      aW[j] = *(const short8*)(W + (size_t)(wn * (16 * NT) + j * 16 + l15) * wld + ko);
#pragma unroll
    for (int i = 0; i < 4; ++i)
      bX[i] = *(const short8*)(Xs + (wm * 64 + i * 16 + l15) * LDXP + ko);
#pragma unroll
    for (int i = 0; i < 4; ++i)
#pragma unroll
      for (int j = 0; j < NT; ++j)
        acc[i][j] = __builtin_amdgcn_mfma_f32_16x16x32_bf16(aW[j], bX[i], acc[i][j], 0, 0, 0);
  }
}

// A8 = fp8(relu(x@W1.T+b1)) [spmm-only], C = relu(x@W2.T+b2) bf16 + C8 fp8.
__global__ __launch_bounds__(256, 2) void gemm_dual_f32_kernel(
    const float* __restrict__ X, const unsigned short* __restrict__ W1,
    const unsigned short* __restrict__ W2, const float* __restrict__ b1,
    const float* __restrict__ b2, unsigned char* __restrict__ A8,
    unsigned short* __restrict__ C, unsigned char* __restrict__ C8, int n)
{
  constexpr int NT = 4;  // HOUT = 128
  __shared__ unsigned short Xs[128 * LDXP];
  const int tid = threadIdx.x;
  const int lane = tid & 63;
  const int wave = tid >> 6;
  const int wm = wave >> 1;
  const int wn = wave & 1;
  const int l15 = lane & 15;
  const int quad = lane >> 4;
  const int row0 = blockIdx.x * 128;
  const int c8 = (tid & 15) * 8;
  const int rloc = tid >> 4;

#pragma unroll
  for (int p = 0; p < 8; ++p) {
    int r = p * 16 + rloc;
    int gr = row0 + r;
    uint4 o = make_uint4(0u, 0u, 0u, 0u);
    if (gr < n) {
      float4 f0 = *(const float4*)(X + (size_t)gr * 128 + c8);
      float4 f1 = *(const float4*)(X + (size_t)gr * 128 + c8 + 4);
      o.x = pack2(f0.x, f0.y); o.y = pack2(f0.z, f0.w);
      o.z = pack2(f1.x, f1.y); o.w = pack2(f1.z, f1.w);
    }
    *(uint4*)(Xs + r * LDXP + c8) = o;
  }
  __syncthreads();

  for (int s = 0; s < 2; ++s) {
    const unsigned short* W = s ? W2 : W1;
    const float* b = s ? b2 : b1;
    floatx4 acc[4][NT];
#pragma unroll
    for (int i = 0; i < 4; ++i)
#pragma unroll
      for (int j = 0; j < NT; ++j) acc[i][j] = (floatx4){0.f, 0.f, 0.f, 0.f};
    mfma_phase<NT>(W, 128, Xs, wm, wn, l15, quad, acc);
#pragma unroll
    for (int i = 0; i < 4; ++i) {
      int r = row0 + wm * 64 + i * 16 + l15;
      if (r >= n) continue;
#pragma unroll
      for (int j = 0; j < NT; ++j) {
        int c0 = wn * 64 + j * 16 + quad * 4;
        float4 bb = *(const float4*)(b + c0);
        float v0 = fmaxf(acc[i][j][0] + bb.x, 0.f);
        float v1 = fmaxf(acc[i][j][1] + bb.y, 0.f);
        float v2 = fmaxf(acc[i][j][2] + bb.z, 0.f);
        float v3 = fmaxf(acc[i][j][3] + bb.w, 0.f);
        unsigned p8 = pack_fp8x4(v0, v1, v2, v3);
        if (s == 0) {
          *(unsigned*)(A8 + (size_t)r * 128 + c0) = p8;      // A: fp8 only
        } else {
          uint2 o; o.x = pack2(v0, v1); o.y = pack2(v2, v3);
          *(uint2*)(C + (size_t)r * 128 + c0) = o;           // C: bf16 (GEMM)
          *(unsigned*)(C8 + (size_t)r * 128 + c0) = p8;      // C: fp8 (spmm)
        }
      }
    }
  }
}

// y=0: Q8 = fp8((relu(B·Wa1^T+ba1))·Wo0^T) (chained through LDS, spmm-only)
// y=1: D = relu(B2·Wb1^T+bb1) bf16 + D8 fp8
__global__ __launch_bounds__(256, 2) void chain_g1_kernel(
    const unsigned short* __restrict__ B, const unsigned short* __restrict__ Wa1,
    const float* __restrict__ ba1, const unsigned short* __restrict__ Wo0,
    unsigned char* __restrict__ Q8,
    const unsigned short* __restrict__ B2, const unsigned short* __restrict__ Wb1,
    const float* __restrict__ bb1, unsigned short* __restrict__ D,
    unsigned char* __restrict__ D8, int n)
{
  __shared__ unsigned short Xs[128 * LDXP];
  const int tid = threadIdx.x;
  const int lane = tid & 63;
  const int wave = tid >> 6;
  const int wm = wave >> 1;
  const int wn = wave & 1;
  const int l15 = lane & 15;
  const int quad = lane >> 4;
  const int row0 = blockIdx.x * 128;
  const int c8 = (tid & 15) * 8;
  const int rloc = tid >> 4;

  if (blockIdx.y == 0) {
    stage_bf16(B, Xs, row0, n, rloc, c8);
    __syncthreads();

    floatx4 acc1[4][4];
#pragma unroll
    for (int i = 0; i < 4; ++i)
#pragma unroll
      for (int j = 0; j < 4; ++j) acc1[i][j] = (floatx4){0.f, 0.f, 0.f, 0.f};
    mfma_phase<4>(Wa1, 128, Xs, wm, wn, l15, quad, acc1);
    __syncthreads();   // all stage-1 reads of Xs done before overwrite

    // A2 = relu(acc1 + ba1) -> Xs (bf16)
#pragma unroll
    for (int i = 0; i < 4; ++i) {
      int r2 = wm * 64 + i * 16 + l15;
#pragma unroll
      for (int j = 0; j < 4; ++j) {
        int c2 = wn * 64 + j * 16 + quad * 4;
        float4 bb = *(const float4*)(ba1 + c2);
        float v0 = fmaxf(acc1[i][j][0] + bb.x, 0.f);
        float v1 = fmaxf(acc1[i][j][1] + bb.y, 0.f);
        float v2 = fmaxf(acc1[i][j][2] + bb.z, 0.f);
        float v3 = fmaxf(acc1[i][j][3] + bb.w, 0.f);
        uint2 o; o.x = pack2(v0, v1); o.y = pack2(v2, v3);
        *(uint2*)(Xs + r2 * LDXP + c2) = o;
      }
    }
    __syncthreads();

    floatx4 acc2[4][2];
#pragma unroll
    for (int i = 0; i < 4; ++i)
#pragma unroll
      for (int j = 0; j < 2; ++j) acc2[i][j] = (floatx4){0.f, 0.f, 0.f, 0.f};
    mfma_phase<2>(Wo0, 128, Xs, wm, wn, l15, quad, acc2);

#pragma unroll
    for (int i = 0; i < 4; ++i) {
      int r = row0 + wm * 64 + i * 16 + l15;
      if (r >= n) continue;
#pragma unroll
      for (int j = 0; j < 2; ++j) {
        int c0 = wn * 32 + j * 16 + quad * 4;
        unsigned p8 = pack_fp8x4(acc2[i][j][0], acc2[i][j][1],
                                 acc2[i][j][2], acc2[i][j][3]);
        *(unsigned*)(Q8 + (size_t)r * 64 + c0) = p8;
      }
    }
  } else {
    stage_bf16(B2, Xs, row0, n, rloc, c8);
    __syncthreads();

    floatx4 acc[4][4];
#pragma unroll
    for (int i = 0; i < 4; ++i)
#pragma unroll
      for (int j = 0; j < 4; ++j) acc[i][j] = (floatx4){0.f, 0.f, 0.f, 0.f};
    mfma_phase<4>(Wb1, 128, Xs, wm, wn, l15, quad, acc);

#pragma unroll
    for (int i = 0; i < 4; ++i) {
      int r = row0 + wm * 64 + i * 16 + l15;
      if (r >= n) continue;
#pragma unroll
      for (int j = 0; j < 4; ++j) {
        int c0 = wn * 64 + j * 16 + quad * 4;
        float4 bb = *(const float4*)(bb1 + c0);
        float v0 = fmaxf(acc[i][j][0] + bb.x, 0.f);
        float v1 = fmaxf(acc[i][j][1] + bb.y, 0.f);
        float v2 = fmaxf(acc[i][j][2] + bb.z, 0.f);
        float v3 = fmaxf(acc[i][j][3] + bb.w, 0.f);
        uint2 o; o.x = pack2(v0, v1); o.y = pack2(v2, v3);
        *(uint2*)(D + (size_t)r * 128 + c0) = o;             // bf16 (GEMM)
        *(unsigned*)(D8 + (size_t)r * 128 + c0) = pack_fp8x4(v0, v1, v2, v3);
      }
    }
  }
}

// out = relu(C·Wm0 + D·Wm1 + G2·Wm2 + bm)·Wo1^T + bo + Pout  (A3 in LDS only)
__global__ __launch_bounds__(256, 2) void wm_final_kernel(
    const unsigned short* __restrict__ C, const unsigned short* __restrict__ D,
    const unsigned short* __restrict__ G2,
    const unsigned short* __restrict__ Wm, const float* __restrict__ bm,
    const unsigned short* __restrict__ Wo1, const float* __restrict__ bo,
    const float* __restrict__ Pout, float* __restrict__ out, int n)
{
  __shared__ unsigned short Xs[128 * LDXP];
  const int tid = threadIdx.x;
  const int lane = tid & 63;
  const int wave = tid >> 6;
  const int wm_ = wave >> 1;
  const int wn = wave & 1;
  const int l15 = lane & 15;
  const int quad = lane >> 4;
  const int row0 = blockIdx.x * 128;
  const int c8 = (tid & 15) * 8;
  const int rloc = tid >> 4;

  floatx4 acc[4][4];
#pragma unroll
  for (int i = 0; i < 4; ++i)
#pragma unroll
    for (int j = 0; j < 4; ++j) acc[i][j] = (floatx4){0.f, 0.f, 0.f, 0.f};

  const unsigned short* Xp[3] = {C, D, G2};
#pragma unroll
  for (int s = 0; s < 3; ++s) {
    if (s) __syncthreads();
    stage_bf16(Xp[s], Xs, row0, n, rloc, c8);
    __syncthreads();
    mfma_phase<4>(Wm + s * 128, 384, Xs, wm_, wn, l15, quad, acc);
  }
  __syncthreads();   // all K=384 reads done before A3 overwrite

  // A3 = relu(acc + bm) -> Xs (bf16)
#pragma unroll
  for (int i = 0; i < 4; ++i) {
    int r2 = wm_ * 64 + i * 16 + l15;
#pragma unroll
    for (int j = 0; j < 4; ++j) {
      int c2 = wn * 64 + j * 16 + quad * 4;
      float4 bb = *(const float4*)(bm + c2);
      float v0 = fmaxf(acc[i][j][0] + bb.x, 0.f);
      float v1 = fmaxf(acc[i][j][1] + bb.y, 0.f);
      float v2 = fmaxf(acc[i][j][2] + bb.z, 0.f);
      float v3 = fmaxf(acc[i][j][3] + bb.w, 0.f);
      uint2 o; o.x = pack2(v0, v1); o.y = pack2(v2, v3);
      *(uint2*)(Xs + r2 * LDXP + c2) = o;
    }
  }
  __syncthreads();

  floatx4 acc2[4][2];
#pragma unroll
  for (int i = 0; i < 4; ++i)
#pragma unroll
    for (int j = 0; j < 2; ++j) acc2[i][j] = (floatx4){0.f, 0.f, 0.f, 0.f};
  mfma_phase<2>(Wo1, 128, Xs, wm_, wn, l15, quad, acc2);

#pragma unroll
  for (int i = 0; i < 4; ++i) {
    int r = row0 + wm_ * 64 + i * 16 + l15;
    if (r >= n) continue;
#pragma unroll
    for (int j = 0; j < 2; ++j) {
      int c0 = wn * 32 + j * 16 + quad * 4;
      float4 bb = *(const float4*)(bo + c0);
      float4 pv = *(const float4*)(Pout + (size_t)r * 64 + c0);
      float4 o;
      o.x = acc2[i][j][0] + bb.x + pv.x;
      o.y = acc2[i][j][1] + bb.y + pv.y;
      o.z = acc2[i][j][2] + bb.z + pv.z;
      o.w = acc2[i][j][3] + bb.w + pv.w;
      *(float4*)(out + (size_t)r * 64 + c0) = o;
    }
  }
}

extern "C" void kernel_launch(void* const* d_in, const int* in_sizes, int n_in,
                              void* d_out, int out_size, void* d_ws, size_t ws_size,
                              hipStream_t stream)
{
  const float* x     = (const float*)d_in[0];
  const int*   row_a = (const int*)d_in[1];
  const int*   col_a = (const int*)d_in[2];
  const float* val_a = (const float*)d_in[3];
  const int*   row_b = (const int*)d_in[4];
  const int*   col_b = (const int*)d_in[5];
  const float* val_b = (const float*)d_in[6];
  const float* Wa0 = (const float*)d_in[7];  const float* ba0 = (const float*)d_in[8];
  const float* Wa1 = (const float*)d_in[9];  const float* ba1 = (const float*)d_in[10];
  const float* Wb0 = (const float*)d_in[11]; const float* bb0 = (const float*)d_in[12];
  const float* Wb1 = (const float*)d_in[13]; const float* bb1 = (const float*)d_in[14];
  const float* Wm  = (const float*)d_in[15]; const float* bm  = (const float*)d_in[16];
  const float* Wo  = (const float*)d_in[17]; const float* bo  = (const float*)d_in[18];
  float* out = (float*)d_out;

  const int n = in_sizes[0] / 128;   // 50000
  const int E = in_sizes[1];         // 800000

  char* ws = (char*)d_ws;
  size_t off = 0;
  auto alloc = [&](size_t bytes) {
    void* p = ws + off;
    off = (off + bytes + 255) & ~(size_t)255;
    return p;
  };
  int* rpa = (int*)alloc((size_t)(n + 1) * sizeof(int));
  int* rpb = (int*)alloc((size_t)(n + 1) * sizeof(int));
  unsigned short* Wcat = (unsigned short*)alloc(131072 * sizeof(unsigned short));
  const size_t slab = (size_t)n * 128 * sizeof(unsigned short);
  const size_t slab8 = (size_t)n * 128;           // fp8 slab (bytes)
  unsigned char*  A8 = (unsigned char*)alloc(slab8);   // fp8 relu(x Wa0 + ba0)
  unsigned short* C  = (unsigned short*)alloc(slab);   // g0 bf16
  unsigned char*  C8 = (unsigned char*)alloc(slab8);   // g0 fp8
  unsigned short* B  = (unsigned short*)alloc(slab);   // graph-a sp1 out / g2
  unsigned short* B2 = (unsigned short*)alloc(slab);   // graph-b sp1 out
  unsigned short* D  = (unsigned short*)alloc(slab);   // g1 bf16
  unsigned char*  D8 = (unsigned char*)alloc(slab8);   // g1 fp8
  unsigned char*  Q8 = (unsigned char*)alloc((size_t)n * 64);  // fp8 Q
  float* Pout = (float*)alloc((size_t)n * 64 * sizeof(float)); // x_a @ Wo0^T

  const unsigned short* Wa0b = Wcat;
  const unsigned short* Wa1b = Wcat + 16384;
  const unsigned short* Wb0b = Wcat + 32768;
  const unsigned short* Wb1b = Wcat + 49152;
  const unsigned short* Wmb  = Wcat + 65536;   // [128, 384]
  const unsigned short* Wo0b = Wcat + 114688;
  const unsigned short* Wo1b = Wcat + 122880;

  dim3 blk(256);
  dim3 g_setup((n + 1 + 255) / 256, 3);
  dim3 g_lin((n + 127) / 128);
  dim3 g_cg((n + 127) / 128, 2);
  dim3 g_sp2((n + 31) / 32, 2);      // 32 rows/block (8 lanes/row, 128-wide)

  setup_kernel<<<g_setup, blk, 0, stream>>>(row_a, row_b, E, n, rpa, rpb,
                                            Wa0, Wa1, Wb0, Wb1, Wm, Wo, Wcat);

  // A8 = fp8(relu(x Wa0^T + ba0)), C = relu(x Wb0^T + bb0) (bf16 + fp8)
  gemm_dual_f32_kernel<<<g_lin, blk, 0, stream>>>(x, Wa0b, Wb0b, ba0, bb0,
                                                  A8, C, C8, n);

  // spmm_a(A8->B) || spmm_b(C8->B2)   (fp8 gathers, 16B/lane)
  spmm_dual128_kernel<<<g_sp2, blk, 0, stream>>>(
      rpa, col_a, val_a, A8, B,
      rpb, col_b, val_b, C8, B2, n);

  // chain: Q8 = fp8(relu(B Wa1^T + ba1) Wo0^T)  ||  g1: D (bf16+fp8)
  chain_g1_kernel<<<g_cg, blk, 0, stream>>>(
      B, Wa1b, ba1, Wo0b, Q8,
      B2, Wb1b, bb1, D, D8, n);

  // g2 = spmm_b(D8) -> B  ||  Pout = spmm_a(Q8)
  spmm_mixed_kernel<<<g_sp2, blk, 0, stream>>>(
      rpb, col_b, val_b, D8, B,
      rpa, col_a, val_a, Q8, Pout, n);

  // out = relu(g0 Wm0 + g1 Wm1 + g2 Wm2 + bm) Wo1^T + bo + Pout
  wm_final_kernel<<<g_lin, blk, 0, stream>>>(
      C, D, B, Wmb, bm, Wo1b, bo, Pout, out, n);
}